// Round 1
// baseline (179.706 us; speedup 1.0000x reference)
//
#include <hip/hip_runtime.h>
#include <hip/hip_bf16.h>
#include <stdint.h>

// Problem dims (fixed by reference)
#define R_TOTAL 1024      // B*S
#define I_DIM   4096
#define OUT_DIM 4096
#define N_STR   32
#define Q_DIM   128

typedef __attribute__((ext_vector_type(8))) __bf16 bf16x8;
typedef __attribute__((ext_vector_type(4))) float  f32x4;

__device__ __forceinline__ ushort f2bf(float f) {
    uint32_t u = __float_as_uint(f);
    uint32_t r = (u + 0x7fffu + ((u >> 16) & 1u)) >> 16;   // RNE
    return (ushort)r;
}

// ---------------- pre-pass 1: thresholds [I][N] -> thT [N][I] ----------------
__global__ __launch_bounds__(256) void k_transpose_th(const float* __restrict__ th,
                                                      float* __restrict__ thT) {
    int idx = blockIdx.x * 256 + threadIdx.x;   // 131072 total
    int n = idx >> 12;                           // idx / 4096
    int i = idx & 4095;
    thT[idx] = th[i * N_STR + n];
}

// ---------------- pre-pass 2: W [I][OUT] f32 -> WT [OUT][I] bf16 -------------
__global__ __launch_bounds__(256) void k_transpose_w(const float* __restrict__ W,
                                                     ushort* __restrict__ WT) {
    __shared__ float tile[64][65];               // +1 pad: conflict-free col reads
    int c0 = blockIdx.x * 64;                    // OUT block
    int i0 = blockIdx.y * 64;                    // I block
    int t = threadIdx.x;
    {
        int dc4 = (t & 15) * 4;
        int di  = t >> 4;                        // 0..15
        #pragma unroll
        for (int p = 0; p < 4; ++p) {
            int ii = di + p * 16;
            float4 v = *(const float4*)(W + (size_t)(i0 + ii) * OUT_DIM + c0 + dc4);
            tile[ii][dc4 + 0] = v.x; tile[ii][dc4 + 1] = v.y;
            tile[ii][dc4 + 2] = v.z; tile[ii][dc4 + 3] = v.w;
        }
    }
    __syncthreads();
    {
        int iq = (t & 15) * 4;
        int dc = t >> 4;                         // 0..15
        #pragma unroll
        for (int p = 0; p < 4; ++p) {
            int cc = dc + p * 16;
            ushort4 o;
            o.x = f2bf(tile[iq + 0][cc]);
            o.y = f2bf(tile[iq + 1][cc]);
            o.z = f2bf(tile[iq + 2][cc]);
            o.w = f2bf(tile[iq + 3][cc]);
            *(ushort4*)(WT + (size_t)(c0 + cc) * I_DIM + i0 + iq) = o;
        }
    }
}

// ---------------- main: per-stripe masked GEMM via bf16 MFMA -----------------
// grid 256: block -> (stripe n, row-tile mt), XCD-grouped (bid&7 assumed = XCD)
// block tile 128x128, BK=64, 512 threads = 8 waves, wave tile 64x32 (4x2 frags)
#define BM 128
#define BN 128
#define BK 64

__global__ __launch_bounds__(512) void k_main(const float* __restrict__ x,
                                              const ushort* __restrict__ WT,
                                              const float* __restrict__ thT,
                                              const float* __restrict__ mu,
                                              const float* __restrict__ out_mu,
                                              float* __restrict__ out) {
    int bid  = blockIdx.x;
    int xcd  = bid & 7;
    int slot = bid >> 3;                   // 0..31
    int n    = xcd * 4 + (slot >> 3);      // stripe 0..31
    int mt   = slot & 7;                   // row tile 0..7
    int r0   = mt * BM;
    int cbase = n * Q_DIM;

    __shared__ ushort sA[BM * BK];         // [row][k] bf16, kbyte ^= (row&7)<<4
    __shared__ ushort sB[BN * BK];         // [col][k] bf16, same swizzle

    int tid  = threadIdx.x;
    int lane = tid & 63;
    int wave = tid >> 6;                   // 0..7
    int wr   = wave >> 2;                  // 0..1 : 64-row block
    int wc   = wave & 3;                   // 0..3 : 32-col block

    f32x4 acc[4][2];
    #pragma unroll
    for (int m2 = 0; m2 < 4; ++m2)
        #pragma unroll
        for (int nn = 0; nn < 2; ++nn)
            acc[m2][nn] = (f32x4){0.f, 0.f, 0.f, 0.f};

    // staging maps
    const int a_kq  = (tid & 15) * 4;      // k elem offset (0..60 step 4)
    const int a_rb  = tid >> 4;            // 0..31, rows step 32
    const int b_ko  = (tid & 7) * 8;       // k elem offset (0..56 step 8)
    const int b_cb  = tid >> 3;            // 0..63, cols step 64
    const int lrow  = lane & 15;
    const int lgrp  = lane >> 4;

    for (int kt = 0; kt < I_DIM / BK; ++kt) {
        int k0 = kt * BK;
        // broadcast vectors (same for all 4 A passes)
        float4 thv = *(const float4*)(thT + (size_t)n * I_DIM + k0 + a_kq);
        float4 muv = *(const float4*)(mu + k0 + a_kq);
        // ---- A staging: masked x -> bf16, 4 passes of 32 rows ----
        #pragma unroll
        for (int p = 0; p < 4; ++p) {
            int row = a_rb + p * 32;
            float4 xv = *(const float4*)(x + (size_t)(r0 + row) * I_DIM + k0 + a_kq);
            float v0 = xv.x - muv.x, v1 = xv.y - muv.y, v2 = xv.z - muv.z, v3 = xv.w - muv.w;
            v0 = (fabsf(v0) >= thv.x) ? v0 : 0.f;
            v1 = (fabsf(v1) >= thv.y) ? v1 : 0.f;
            v2 = (fabsf(v2) >= thv.z) ? v2 : 0.f;
            v3 = (fabsf(v3) >= thv.w) ? v3 : 0.f;
            uint2 pk;
            pk.x = (uint32_t)f2bf(v0) | ((uint32_t)f2bf(v1) << 16);
            pk.y = (uint32_t)f2bf(v2) | ((uint32_t)f2bf(v3) << 16);
            int kbyte = (a_kq * 2) ^ ((row & 7) << 4);
            *(uint2*)((char*)sA + row * (BK * 2) + kbyte) = pk;
        }
        // ---- B staging: WT bf16 rows (k-contiguous), 2 passes of 64 cols ----
        #pragma unroll
        for (int p = 0; p < 2; ++p) {
            int col = b_cb + p * 64;
            uint4 wv = *(const uint4*)(WT + (size_t)(cbase + col) * I_DIM + k0 + b_ko);
            int kbyte = (b_ko * 2) ^ ((col & 7) << 4);
            *(uint4*)((char*)sB + col * (BK * 2) + kbyte) = wv;
        }
        __syncthreads();
        // ---- compute: 2 k-slices of 32 ----
        #pragma unroll
        for (int ks = 0; ks < 2; ++ks) {
            int kb = ks * 64 + (lgrp << 4);          // kbyte base for this lane
            bf16x8 af[4], bfr[2];
            #pragma unroll
            for (int m2 = 0; m2 < 4; ++m2) {
                int row = wr * 64 + m2 * 16 + lrow;
                af[m2] = *(const bf16x8*)((const char*)sA + row * (BK * 2) + (kb ^ ((row & 7) << 4)));
            }
            #pragma unroll
            for (int nn = 0; nn < 2; ++nn) {
                int col = wc * 32 + nn * 16 + lrow;
                bfr[nn] = *(const bf16x8*)((const char*)sB + col * (BK * 2) + (kb ^ ((col & 7) << 4)));
            }
            #pragma unroll
            for (int m2 = 0; m2 < 4; ++m2)
                #pragma unroll
                for (int nn = 0; nn < 2; ++nn)
                    acc[m2][nn] = __builtin_amdgcn_mfma_f32_16x16x32_bf16(af[m2], bfr[nn], acc[m2][nn], 0, 0, 0);
        }
        __syncthreads();
    }

    // ---- epilogue: D mapping col=lane&15, row=(lane>>4)*4+reg ----
    #pragma unroll
    for (int nn = 0; nn < 2; ++nn) {
        int col = cbase + wc * 32 + nn * 16 + lrow;
        float om = out_mu[col];
        #pragma unroll
        for (int m2 = 0; m2 < 4; ++m2) {
            int rbase = r0 + wr * 64 + m2 * 16 + lgrp * 4;
            #pragma unroll
            for (int j = 0; j < 4; ++j)
                out[(size_t)(rbase + j) * OUT_DIM + col] = acc[m2][nn][j] + om;
        }
    }
}

// ---------------- fallback (ws too small): naive fp32, correct but slow ------
__global__ __launch_bounds__(256) void k_naive(const float* __restrict__ x,
                                               const float* __restrict__ W,
                                               const float* __restrict__ th,
                                               const float* __restrict__ mu,
                                               const float* __restrict__ out_mu,
                                               float* __restrict__ out) {
    int idx = blockIdx.x * 256 + threadIdx.x;   // over R_TOTAL*OUT_DIM
    int r = idx >> 12;
    int c = idx & 4095;
    int n = c >> 7;
    float s = 0.f;
    for (int i = 0; i < I_DIM; ++i) {
        float xo = x[(size_t)r * I_DIM + i] - mu[i];
        if (fabsf(xo) >= th[i * N_STR + n])
            s += xo * W[(size_t)i * OUT_DIM + c];
    }
    out[idx] = s + out_mu[c];
}

extern "C" void kernel_launch(void* const* d_in, const int* in_sizes, int n_in,
                              void* d_out, int out_size, void* d_ws, size_t ws_size,
                              hipStream_t stream) {
    const float* x      = (const float*)d_in[0];
    const float* W      = (const float*)d_in[1];
    const float* th     = (const float*)d_in[2];
    const float* mu     = (const float*)d_in[3];
    const float* out_mu = (const float*)d_in[4];
    float* out = (float*)d_out;

    const size_t thT_bytes = (size_t)N_STR * I_DIM * sizeof(float);      // 512 KiB
    const size_t wT_bytes  = (size_t)OUT_DIM * I_DIM * sizeof(ushort);   // 32 MiB
    if (ws_size < thT_bytes + wT_bytes) {
        k_naive<<<(R_TOTAL * OUT_DIM) / 256, 256, 0, stream>>>(x, W, th, mu, out_mu, out);
        return;
    }
    float*  thT = (float*)d_ws;
    ushort* WT  = (ushort*)((char*)d_ws + thT_bytes);

    k_transpose_th<<<(N_STR * I_DIM) / 256, 256, 0, stream>>>(th, thT);
    k_transpose_w<<<dim3(OUT_DIM / 64, I_DIM / 64), 256, 0, stream>>>(W, WT);
    k_main<<<256, 512, 0, stream>>>(x, WT, thT, mu, out_mu, out);
}

// Round 2
// 170.325 us; speedup vs baseline: 1.0551x; 1.0551x over previous
//
#include <hip/hip_runtime.h>
#include <hip/hip_bf16.h>
#include <stdint.h>

// Problem dims (fixed by reference)
#define R_TOTAL 1024      // B*S
#define I_DIM   4096
#define OUT_DIM 4096
#define N_STR   32
#define Q_DIM   128

typedef __attribute__((ext_vector_type(8))) __bf16 bf16x8;
typedef __attribute__((ext_vector_type(4))) float  f32x4;

__device__ __forceinline__ ushort f2bf(float f) {
    uint32_t u = __float_as_uint(f);
    uint32_t r = (u + 0x7fffu + ((u >> 16) & 1u)) >> 16;   // RNE
    return (ushort)r;
}

// expand 2 mask bits (2w, 2w+1) -> 32-bit AND-mask for a packed bf16 pair
__device__ __forceinline__ uint32_t bexp(uint32_t b, int w) {
    return ((b >> (2 * w)) & 1u) * 0xFFFFu | ((b >> (2 * w + 1)) & 1u) * 0xFFFF0000u;
}

__device__ __forceinline__ void async16(void* lds, const void* g) {
    __builtin_amdgcn_global_load_lds(
        (const __attribute__((address_space(1))) unsigned int*)g,
        (__attribute__((address_space(3))) unsigned int*)lds, 16, 0, 0);
}

// ---------------- pre-pass 1: thresholds [I][N] -> thT [N][I] ----------------
__global__ __launch_bounds__(256) void k_transpose_th(const float* __restrict__ th,
                                                      float* __restrict__ thT) {
    int idx = blockIdx.x * 256 + threadIdx.x;   // 131072 total
    int n = idx >> 12;
    int i = idx & 4095;
    thT[idx] = th[i * N_STR + n];
}

// ---------------- pre-pass 2: W [I][OUT] f32 -> WT [OUT][I] bf16 -------------
__global__ __launch_bounds__(256) void k_transpose_w(const float* __restrict__ W,
                                                     ushort* __restrict__ WT) {
    __shared__ float tile[64][65];
    int c0 = blockIdx.x * 64;                    // OUT block
    int i0 = blockIdx.y * 64;                    // I block
    int t = threadIdx.x;
    {
        int dc4 = (t & 15) * 4;
        int di  = t >> 4;
        #pragma unroll
        for (int p = 0; p < 4; ++p) {
            int ii = di + p * 16;
            float4 v = *(const float4*)(W + (size_t)(i0 + ii) * OUT_DIM + c0 + dc4);
            tile[ii][dc4 + 0] = v.x; tile[ii][dc4 + 1] = v.y;
            tile[ii][dc4 + 2] = v.z; tile[ii][dc4 + 3] = v.w;
        }
    }
    __syncthreads();
    {
        int iq = (t & 15) * 4;
        int dc = t >> 4;
        #pragma unroll
        for (int p = 0; p < 4; ++p) {
            int cc = dc + p * 16;
            ushort4 o;
            o.x = f2bf(tile[iq + 0][cc]);
            o.y = f2bf(tile[iq + 1][cc]);
            o.z = f2bf(tile[iq + 2][cc]);
            o.w = f2bf(tile[iq + 3][cc]);
            *(ushort4*)(WT + (size_t)(c0 + cc) * I_DIM + i0 + iq) = o;
        }
    }
}

// ---------------- pre-pass 3: XB = bf16(x-mu), per-stripe bitmasks -----------
// grid 4096: block = (row-block rb of 4 rows) x (i-block ib of 256)
__global__ __launch_bounds__(256) void k_prep(const float* __restrict__ x,
                                              const float* __restrict__ mu,
                                              const float* __restrict__ thT,
                                              ushort* __restrict__ XB,
                                              unsigned long long* __restrict__ MB64) {
    int b  = blockIdx.x;
    int rb = b >> 4;                 // 0..255
    int ib = b & 15;
    int tid = threadIdx.x;
    int i = ib * 256 + tid;
    int lane = tid & 63;
    int wave = tid >> 6;
    int iw = ib * 4 + wave;          // u64 word index within a 4096-bit row

    float muv = mu[i];
    float ax[4];
    #pragma unroll
    for (int rr = 0; rr < 4; ++rr) {
        int r = rb * 4 + rr;
        float xo = x[(size_t)r * I_DIM + i] - muv;
        XB[(size_t)r * I_DIM + i] = f2bf(xo);
        ax[rr] = fabsf(xo);
    }
    for (int n = 0; n < N_STR; ++n) {
        float t = thT[(size_t)n * I_DIM + i];
        #pragma unroll
        for (int rr = 0; rr < 4; ++rr) {
            unsigned long long bal = __ballot(ax[rr] >= t);
            if (lane == 0)
                MB64[((size_t)n * R_TOTAL + rb * 4 + rr) * 64 + iw] = bal;
        }
    }
}

// ---------------- main v2: 2-phase pipelined masked GEMM ---------------------
// tile 128x128, BK=64, 512 threads / 8 waves, wave tile 64x32, dbuf LDS 64KB
#define BM 128
#define BN 128
#define BK 64
#define TILEB 16384   // bytes per LDS tile (128*64*2)

__global__ __launch_bounds__(512) void k_main2(const ushort* __restrict__ XB,
                                               const ushort* __restrict__ WT,
                                               const uint8_t* __restrict__ MB,
                                               const float* __restrict__ out_mu,
                                               float* __restrict__ out) {
    __shared__ ushort sA[2][BM * BK];
    __shared__ ushort sB[2][BN * BK];

    int bid  = blockIdx.x;
    int xcd  = bid & 7;
    int slot = bid >> 3;
    int n    = xcd * 4 + (slot >> 3);      // stripe
    int mt   = slot & 7;                   // row tile
    int r0   = mt * BM;
    int cbase = n * Q_DIM;

    int tid  = threadIdx.x;
    int lane = tid & 63;
    int wave = tid >> 6;
    int wr   = wave >> 2;
    int wc   = wave & 3;
    int lrow = lane & 15;
    int lgrp = lane >> 4;

    // ---- A staging map: thread -> (row, 16 consecutive k)
    int arow  = tid >> 2;                  // 0..127
    int akoff = (tid & 3) << 4;            // element offset 0,16,32,48
    const ushort*  pXB = XB + (size_t)(r0 + arow) * I_DIM + akoff;
    const uint8_t* pMB = MB + ((size_t)n * R_TOTAL + (r0 + arow)) * 512 + (akoff >> 3);
    int aswz = (arow & 7) << 4;
    int aw0  = arow * 128 + ((akoff * 2) ^ aswz);
    int aw1  = arow * 128 + (((akoff * 2) + 16) ^ aswz);

    // ---- B staging map (global_load_lds, pre-swizzled source)
    // chunk c covers cols c*8..c*8+7; lane l: col=c*8+(l>>3), linear kbyte=(l&7)*16
    // source kbyte = linear ^ ((col&7)<<4) = ((l&7)^(l>>3))*16
    int colA0 = wave * 16 + (lane >> 3);
    int kbB   = ((lane & 7) ^ (lane >> 3)) << 4;
    const char* pB0 = (const char*)(WT + (size_t)(cbase + colA0) * I_DIM) + kbB;
    const char* pB1 = pB0 + (size_t)8 * I_DIM * 2;

    f32x4 acc[4][2];
    #pragma unroll
    for (int m2 = 0; m2 < 4; ++m2)
        #pragma unroll
        for (int nn = 0; nn < 2; ++nn)
            acc[m2][nn] = (f32x4){0.f, 0.f, 0.f, 0.f};

    // ---- prologue: stage tile 0 into buffer 0
    {
        uint4 va = *(const uint4*)pXB;
        uint4 vb = *((const uint4*)pXB + 1);
        uint32_t mb = *(const uint16_t*)pMB;
        async16((char*)sB[0] + wave * 2048,        pB0);
        async16((char*)sB[0] + wave * 2048 + 1024, pB1);
        uint4 z0, z1;
        z0.x = va.x & bexp(mb, 0); z0.y = va.y & bexp(mb, 1);
        z0.z = va.z & bexp(mb, 2); z0.w = va.w & bexp(mb, 3);
        z1.x = vb.x & bexp(mb, 4); z1.y = vb.y & bexp(mb, 5);
        z1.z = vb.z & bexp(mb, 6); z1.w = vb.w & bexp(mb, 7);
        *(uint4*)((char*)sA[0] + aw0) = z0;
        *(uint4*)((char*)sA[0] + aw1) = z1;
        __syncthreads();
        pXB += BK; pMB += BK / 8; pB0 += BK * 2; pB1 += BK * 2;
    }

    const int NT = I_DIM / BK;   // 64
    for (int kt = 0; kt < NT; ++kt) {
        int cur = kt & 1;
        int nxt = cur ^ 1;
        bool pf = (kt + 1) < NT;
        uint4 va, vb; uint32_t mb = 0;
        if (pf) {
            va = *(const uint4*)pXB;
            vb = *((const uint4*)pXB + 1);
            mb = *(const uint16_t*)pMB;
            async16((char*)sB[nxt] + wave * 2048,        pB0);
            async16((char*)sB[nxt] + wave * 2048 + 1024, pB1);
            pXB += BK; pMB += BK / 8; pB0 += BK * 2; pB1 += BK * 2;
        }
        // ---- compute current tile
        const char* sAc = (const char*)sA[cur];
        const char* sBc = (const char*)sB[cur];
        #pragma unroll
        for (int ks = 0; ks < 2; ++ks) {
            int kb = ks * 64 + (lgrp << 4);
            bf16x8 af[4], bfr[2];
            #pragma unroll
            for (int m2 = 0; m2 < 4; ++m2) {
                int row = wr * 64 + m2 * 16 + lrow;
                af[m2] = *(const bf16x8*)(sAc + row * 128 + (kb ^ ((row & 7) << 4)));
            }
            #pragma unroll
            for (int nn = 0; nn < 2; ++nn) {
                int col = wc * 32 + nn * 16 + lrow;
                bfr[nn] = *(const bf16x8*)(sBc + col * 128 + (kb ^ ((col & 7) << 4)));
            }
            #pragma unroll
            for (int m2 = 0; m2 < 4; ++m2)
                #pragma unroll
                for (int nn = 0; nn < 2; ++nn)
                    acc[m2][nn] = __builtin_amdgcn_mfma_f32_16x16x32_bf16(af[m2], bfr[nn], acc[m2][nn], 0, 0, 0);
        }
        // ---- finish staging next tile (A transform + LDS write)
        if (pf) {
            uint4 z0, z1;
            z0.x = va.x & bexp(mb, 0); z0.y = va.y & bexp(mb, 1);
            z0.z = va.z & bexp(mb, 2); z0.w = va.w & bexp(mb, 3);
            z1.x = vb.x & bexp(mb, 4); z1.y = vb.y & bexp(mb, 5);
            z1.z = vb.z & bexp(mb, 6); z1.w = vb.w & bexp(mb, 7);
            *(uint4*)((char*)sA[nxt] + aw0) = z0;
            *(uint4*)((char*)sA[nxt] + aw1) = z1;
        }
        __syncthreads();
    }

    // ---- epilogue
    #pragma unroll
    for (int nn = 0; nn < 2; ++nn) {
        int col = cbase + wc * 32 + nn * 16 + lrow;
        float om = out_mu[col];
        #pragma unroll
        for (int m2 = 0; m2 < 4; ++m2) {
            int rbase = r0 + wr * 64 + m2 * 16 + lgrp * 4;
            #pragma unroll
            for (int j = 0; j < 4; ++j)
                out[(size_t)(rbase + j) * OUT_DIM + col] = acc[m2][nn][j] + om;
        }
    }
}

// ---------------- fallback v1 (round-1 main, reg-staged from fp32 x) ---------
__global__ __launch_bounds__(512) void k_main1(const float* __restrict__ x,
                                               const ushort* __restrict__ WT,
                                               const float* __restrict__ thT,
                                               const float* __restrict__ mu,
                                               const float* __restrict__ out_mu,
                                               float* __restrict__ out) {
    int bid  = blockIdx.x;
    int xcd  = bid & 7;
    int slot = bid >> 3;
    int n    = xcd * 4 + (slot >> 3);
    int mt   = slot & 7;
    int r0   = mt * BM;
    int cbase = n * Q_DIM;

    __shared__ ushort sA[BM * BK];
    __shared__ ushort sB[BN * BK];

    int tid  = threadIdx.x;
    int lane = tid & 63;
    int wave = tid >> 6;
    int wr   = wave >> 2;
    int wc   = wave & 3;

    f32x4 acc[4][2];
    #pragma unroll
    for (int m2 = 0; m2 < 4; ++m2)
        #pragma unroll
        for (int nn = 0; nn < 2; ++nn)
            acc[m2][nn] = (f32x4){0.f, 0.f, 0.f, 0.f};

    const int a_kq  = (tid & 15) * 4;
    const int a_rb  = tid >> 4;
    const int b_ko  = (tid & 7) * 8;
    const int b_cb  = tid >> 3;
    const int lrow  = lane & 15;
    const int lgrp  = lane >> 4;

    for (int kt = 0; kt < I_DIM / BK; ++kt) {
        int k0 = kt * BK;
        float4 thv = *(const float4*)(thT + (size_t)n * I_DIM + k0 + a_kq);
        float4 muv = *(const float4*)(mu + k0 + a_kq);
        #pragma unroll
        for (int p = 0; p < 4; ++p) {
            int row = a_rb + p * 32;
            float4 xv = *(const float4*)(x + (size_t)(r0 + row) * I_DIM + k0 + a_kq);
            float v0 = xv.x - muv.x, v1 = xv.y - muv.y, v2 = xv.z - muv.z, v3 = xv.w - muv.w;
            v0 = (fabsf(v0) >= thv.x) ? v0 : 0.f;
            v1 = (fabsf(v1) >= thv.y) ? v1 : 0.f;
            v2 = (fabsf(v2) >= thv.z) ? v2 : 0.f;
            v3 = (fabsf(v3) >= thv.w) ? v3 : 0.f;
            uint2 pk;
            pk.x = (uint32_t)f2bf(v0) | ((uint32_t)f2bf(v1) << 16);
            pk.y = (uint32_t)f2bf(v2) | ((uint32_t)f2bf(v3) << 16);
            int kbyte = (a_kq * 2) ^ ((row & 7) << 4);
            *(uint2*)((char*)sA + row * (BK * 2) + kbyte) = pk;
        }
        #pragma unroll
        for (int p = 0; p < 2; ++p) {
            int col = b_cb + p * 64;
            uint4 wv = *(const uint4*)(WT + (size_t)(cbase + col) * I_DIM + k0 + b_ko);
            int kbyte = (b_ko * 2) ^ ((col & 7) << 4);
            *(uint4*)((char*)sB + col * (BK * 2) + kbyte) = wv;
        }
        __syncthreads();
        #pragma unroll
        for (int ks = 0; ks < 2; ++ks) {
            int kb = ks * 64 + (lgrp << 4);
            bf16x8 af[4], bfr[2];
            #pragma unroll
            for (int m2 = 0; m2 < 4; ++m2) {
                int row = wr * 64 + m2 * 16 + lrow;
                af[m2] = *(const bf16x8*)((const char*)sA + row * (BK * 2) + (kb ^ ((row & 7) << 4)));
            }
            #pragma unroll
            for (int nn = 0; nn < 2; ++nn) {
                int col = wc * 32 + nn * 16 + lrow;
                bfr[nn] = *(const bf16x8*)((const char*)sB + col * (BK * 2) + (kb ^ ((col & 7) << 4)));
            }
            #pragma unroll
            for (int m2 = 0; m2 < 4; ++m2)
                #pragma unroll
                for (int nn = 0; nn < 2; ++nn)
                    acc[m2][nn] = __builtin_amdgcn_mfma_f32_16x16x32_bf16(af[m2], bfr[nn], acc[m2][nn], 0, 0, 0);
        }
        __syncthreads();
    }

    #pragma unroll
    for (int nn = 0; nn < 2; ++nn) {
        int col = cbase + wc * 32 + nn * 16 + lrow;
        float om = out_mu[col];
        #pragma unroll
        for (int m2 = 0; m2 < 4; ++m2) {
            int rbase = r0 + wr * 64 + m2 * 16 + lgrp * 4;
            #pragma unroll
            for (int j = 0; j < 4; ++j)
                out[(size_t)(rbase + j) * OUT_DIM + col] = acc[m2][nn][j] + om;
        }
    }
}

// ---------------- fallback: naive fp32 ---------------------------------------
__global__ __launch_bounds__(256) void k_naive(const float* __restrict__ x,
                                               const float* __restrict__ W,
                                               const float* __restrict__ th,
                                               const float* __restrict__ mu,
                                               const float* __restrict__ out_mu,
                                               float* __restrict__ out) {
    int idx = blockIdx.x * 256 + threadIdx.x;
    int r = idx >> 12;
    int c = idx & 4095;
    int n = c >> 7;
    float s = 0.f;
    for (int i = 0; i < I_DIM; ++i) {
        float xo = x[(size_t)r * I_DIM + i] - mu[i];
        if (fabsf(xo) >= th[i * N_STR + n])
            s += xo * W[(size_t)i * OUT_DIM + c];
    }
    out[idx] = s + out_mu[c];
}

extern "C" void kernel_launch(void* const* d_in, const int* in_sizes, int n_in,
                              void* d_out, int out_size, void* d_ws, size_t ws_size,
                              hipStream_t stream) {
    const float* x      = (const float*)d_in[0];
    const float* W      = (const float*)d_in[1];
    const float* th     = (const float*)d_in[2];
    const float* mu     = (const float*)d_in[3];
    const float* out_mu = (const float*)d_in[4];
    float* out = (float*)d_out;

    const size_t thT_b = (size_t)N_STR * I_DIM * sizeof(float);      // 512 KiB
    const size_t wT_b  = (size_t)OUT_DIM * I_DIM * sizeof(ushort);   // 32 MiB
    const size_t xb_b  = (size_t)R_TOTAL * I_DIM * sizeof(ushort);   // 8 MiB
    const size_t mb_b  = (size_t)N_STR * R_TOTAL * 512;              // 16 MiB

    if (ws_size >= thT_b + wT_b + xb_b + mb_b) {
        float*  thT = (float*)d_ws;
        ushort* WT  = (ushort*)((char*)d_ws + thT_b);
        ushort* XBp = (ushort*)((char*)d_ws + thT_b + wT_b);
        uint8_t* MBp = (uint8_t*)((char*)d_ws + thT_b + wT_b + xb_b);

        k_transpose_th<<<(N_STR * I_DIM) / 256, 256, 0, stream>>>(th, thT);
        k_prep<<<(R_TOTAL / 4) * 16, 256, 0, stream>>>(x, mu, thT, XBp,
                                                       (unsigned long long*)MBp);
        k_transpose_w<<<dim3(OUT_DIM / 64, I_DIM / 64), 256, 0, stream>>>(W, WT);
        k_main2<<<256, 512, 0, stream>>>(XBp, WT, MBp, out_mu, out);
    } else if (ws_size >= thT_b + wT_b) {
        float*  thT = (float*)d_ws;
        ushort* WT  = (ushort*)((char*)d_ws + thT_b);
        k_transpose_th<<<(N_STR * I_DIM) / 256, 256, 0, stream>>>(th, thT);
        k_transpose_w<<<dim3(OUT_DIM / 64, I_DIM / 64), 256, 0, stream>>>(W, WT);
        k_main1<<<256, 512, 0, stream>>>(x, WT, thT, mu, out_mu, out);
    } else {
        k_naive<<<(R_TOTAL * OUT_DIM) / 256, 256, 0, stream>>>(x, W, th, mu, out_mu, out);
    }
}

// Round 3
// 115.018 us; speedup vs baseline: 1.5624x; 1.4809x over previous
//
#include <hip/hip_runtime.h>
#include <hip/hip_bf16.h>
#include <stdint.h>

// Problem dims (fixed by reference)
#define R_TOTAL 1024      // B*S
#define I_DIM   4096
#define OUT_DIM 4096
#define N_STR   32
#define Q_DIM   128

typedef __attribute__((ext_vector_type(8))) __bf16 bf16x8;
typedef __attribute__((ext_vector_type(4))) float  f32x4;

__device__ __forceinline__ ushort f2bf(float f) {
    uint32_t u = __float_as_uint(f);
    uint32_t r = (u + 0x7fffu + ((u >> 16) & 1u)) >> 16;   // RNE
    return (ushort)r;
}

// expand 2 mask bits (2w, 2w+1) -> 32-bit AND-mask for a packed bf16 pair
__device__ __forceinline__ uint32_t bexp(uint32_t b, int w) {
    return ((b >> (2 * w)) & 1u) * 0xFFFFu | ((b >> (2 * w + 1)) & 1u) * 0xFFFF0000u;
}

__device__ __forceinline__ void async16(void* lds, const void* g) {
    __builtin_amdgcn_global_load_lds(
        (const __attribute__((address_space(1))) unsigned int*)g,
        (__attribute__((address_space(3))) unsigned int*)lds, 16, 0, 0);
}

// ---------------- pre-pass A: thresholds [I][N] -> thT [N][I] (fallback only)
__global__ __launch_bounds__(256) void k_transpose_th(const float* __restrict__ th,
                                                      float* __restrict__ thT) {
    int idx = blockIdx.x * 256 + threadIdx.x;
    int n = idx >> 12;
    int i = idx & 4095;
    thT[idx] = th[i * N_STR + n];
}

// ---------------- pre-pass B: W [I][OUT] f32 -> WT [OUT][I] bf16 -------------
__global__ __launch_bounds__(256) void k_transpose_w(const float* __restrict__ W,
                                                     ushort* __restrict__ WT) {
    __shared__ float tile[64][65];
    int c0 = blockIdx.x * 64;                    // OUT block
    int i0 = blockIdx.y * 64;                    // I block
    int t = threadIdx.x;
    {
        int dc4 = (t & 15) * 4;
        int di  = t >> 4;
        #pragma unroll
        for (int p = 0; p < 4; ++p) {
            int ii = di + p * 16;
            float4 v = *(const float4*)(W + (size_t)(i0 + ii) * OUT_DIM + c0 + dc4);
            tile[ii][dc4 + 0] = v.x; tile[ii][dc4 + 1] = v.y;
            tile[ii][dc4 + 2] = v.z; tile[ii][dc4 + 3] = v.w;
        }
    }
    __syncthreads();
    {
        int iq = (t & 15) * 4;
        int dc = t >> 4;
        #pragma unroll
        for (int p = 0; p < 4; ++p) {
            int cc = dc + p * 16;
            ushort4 o;
            o.x = f2bf(tile[iq + 0][cc]);
            o.y = f2bf(tile[iq + 1][cc]);
            o.z = f2bf(tile[iq + 2][cc]);
            o.w = f2bf(tile[iq + 3][cc]);
            *(ushort4*)(WT + (size_t)(c0 + cc) * I_DIM + i0 + iq) = o;
        }
    }
}

// ---------------- pre-pass C v2: XB = bf16(x-mu) + stripe bitmasks -----------
// grid 2048: rb (128 row-blocks of 8) x ib (16 i-blocks of 256). Coalesced
// mask writes via LDS staging (was scattered lane0 8B stores).
__global__ __launch_bounds__(256) void k_prep2(const float* __restrict__ x,
                                               const float* __restrict__ mu,
                                               const float* __restrict__ th,
                                               ushort* __restrict__ XB,
                                               unsigned long long* __restrict__ MB64) {
    __shared__ unsigned long long sMB[N_STR * 8 * 4];   // [n][rr][wave] 8 KB
    int rb = blockIdx.x >> 4;        // 0..127
    int ib = blockIdx.x & 15;
    int tid = threadIdx.x;
    int i = ib * 256 + tid;
    int lane = tid & 63;
    int wave = tid >> 6;

    float muv = mu[i];
    float ax[8];
    #pragma unroll
    for (int rr = 0; rr < 8; ++rr) {
        int r = rb * 8 + rr;
        float xo = x[(size_t)r * I_DIM + i] - muv;
        XB[(size_t)r * I_DIM + i] = f2bf(xo);
        ax[rr] = fabsf(xo);
    }
    for (int n4 = 0; n4 < 8; ++n4) {
        float4 tv = *(const float4*)(th + (size_t)i * N_STR + n4 * 4);
        #pragma unroll
        for (int j = 0; j < 4; ++j) {
            float t = (j == 0) ? tv.x : (j == 1) ? tv.y : (j == 2) ? tv.z : tv.w;
            int n = n4 * 4 + j;
            #pragma unroll
            for (int rr = 0; rr < 8; ++rr) {
                unsigned long long bal = __ballot(ax[rr] >= t);
                if (lane == 0) sMB[(n * 8 + rr) * 4 + wave] = bal;
            }
        }
    }
    __syncthreads();
    // coalesced write: thread -> (n, rr), 32 contiguous bytes
    int n = tid >> 3, rr = tid & 7;
    const uint4* s = (const uint4*)&sMB[(n * 8 + rr) * 4];
    uint4* dst = (uint4*)((char*)MB64 + ((size_t)n * R_TOTAL + rb * 8 + rr) * 512 + ib * 32);
    dst[0] = s[0];
    dst[1] = s[1];
}

// ---------------- main v3: BM=64, grid 512, 2 blocks/CU ----------------------
#define BM3 64
#define BN3 128
#define BK3 64

__global__ __launch_bounds__(512) void k_main3(const ushort* __restrict__ XB,
                                               const ushort* __restrict__ WT,
                                               const uint8_t* __restrict__ MB,
                                               const float* __restrict__ out_mu,
                                               float* __restrict__ out) {
    __shared__ ushort sA[2][BM3 * BK3];    // 8 KB each
    __shared__ ushort sB[2][BN3 * BK3];    // 16 KB each

    int bid  = blockIdx.x;                 // 0..511
    int xcd  = bid & 7;
    int slot = bid >> 3;                   // 0..63
    int n    = xcd * 4 + (slot >> 4);      // stripe (XCD-local)
    int mt   = slot & 15;                  // row tile 0..15
    int r0   = mt * BM3;
    int cbase = n * Q_DIM;

    int tid  = threadIdx.x;
    int lane = tid & 63;
    int wave = tid >> 6;
    int wr   = wave >> 2;                  // 0..1 : 32-row group
    int wc   = wave & 3;                   // 0..3 : 32-col group
    int lrow = lane & 15;
    int lgrp = lane >> 4;

    // ---- A staging map: thread -> (row, 8 consecutive k)
    int arow  = tid >> 3;                  // 0..63
    int akoff = (tid & 7) << 3;            // 0,8,..,56 elems
    const ushort*  pXB = XB + (size_t)(r0 + arow) * I_DIM + akoff;
    const uint8_t* pMB = MB + ((size_t)n * R_TOTAL + (r0 + arow)) * 512 + (tid & 7);
    int aw = arow * 128 + ((akoff * 2) ^ ((arow & 7) << 4));

    // ---- B staging map (global_load_lds, pre-swizzled source)
    int colA0 = wave * 16 + (lane >> 3);
    int kbB   = ((lane & 7) ^ (lane >> 3)) << 4;
    const char* pB0 = (const char*)(WT + (size_t)(cbase + colA0) * I_DIM) + kbB;
    const char* pB1 = pB0 + (size_t)8 * I_DIM * 2;

    f32x4 acc[2][2];
    #pragma unroll
    for (int m2 = 0; m2 < 2; ++m2)
        #pragma unroll
        for (int nn = 0; nn < 2; ++nn)
            acc[m2][nn] = (f32x4){0.f, 0.f, 0.f, 0.f};

    // ---- prologue: stage tile 0
    {
        uint4 va = *(const uint4*)pXB;
        uint32_t mb = *pMB;
        async16((char*)sB[0] + wave * 2048,        pB0);
        async16((char*)sB[0] + wave * 2048 + 1024, pB1);
        uint4 z;
        z.x = va.x & bexp(mb, 0); z.y = va.y & bexp(mb, 1);
        z.z = va.z & bexp(mb, 2); z.w = va.w & bexp(mb, 3);
        *(uint4*)((char*)sA[0] + aw) = z;
        __syncthreads();
        pXB += BK3; pMB += BK3 / 8; pB0 += BK3 * 2; pB1 += BK3 * 2;
    }

    const int NT = I_DIM / BK3;   // 64
    for (int kt = 0; kt < NT; ++kt) {
        int cur = kt & 1;
        int nxt = cur ^ 1;
        bool pf = (kt + 1) < NT;
        uint4 va; uint32_t mb = 0;
        if (pf) {
            va = *(const uint4*)pXB;
            mb = *pMB;
            async16((char*)sB[nxt] + wave * 2048,        pB0);
            async16((char*)sB[nxt] + wave * 2048 + 1024, pB1);
            pXB += BK3; pMB += BK3 / 8; pB0 += BK3 * 2; pB1 += BK3 * 2;
        }
        // ---- compute current tile
        const char* sAc = (const char*)sA[cur];
        const char* sBc = (const char*)sB[cur];
        #pragma unroll
        for (int ks = 0; ks < 2; ++ks) {
            int kb = ks * 64 + (lgrp << 4);
            bf16x8 af[2], bfr[2];
            #pragma unroll
            for (int m2 = 0; m2 < 2; ++m2) {
                int row = wr * 32 + m2 * 16 + lrow;
                af[m2] = *(const bf16x8*)(sAc + row * 128 + (kb ^ ((row & 7) << 4)));
            }
            #pragma unroll
            for (int nn = 0; nn < 2; ++nn) {
                int col = wc * 32 + nn * 16 + lrow;
                bfr[nn] = *(const bf16x8*)(sBc + col * 128 + (kb ^ ((col & 7) << 4)));
            }
            #pragma unroll
            for (int m2 = 0; m2 < 2; ++m2)
                #pragma unroll
                for (int nn = 0; nn < 2; ++nn)
                    acc[m2][nn] = __builtin_amdgcn_mfma_f32_16x16x32_bf16(af[m2], bfr[nn], acc[m2][nn], 0, 0, 0);
        }
        // ---- finish staging next tile (A mask+write)
        if (pf) {
            uint4 z;
            z.x = va.x & bexp(mb, 0); z.y = va.y & bexp(mb, 1);
            z.z = va.z & bexp(mb, 2); z.w = va.w & bexp(mb, 3);
            *(uint4*)((char*)sA[nxt] + aw) = z;
        }
        __syncthreads();
    }

    // ---- epilogue
    #pragma unroll
    for (int nn = 0; nn < 2; ++nn) {
        int col = cbase + wc * 32 + nn * 16 + lrow;
        float om = out_mu[col];
        #pragma unroll
        for (int m2 = 0; m2 < 2; ++m2) {
            int rbase = r0 + wr * 32 + m2 * 16 + lgrp * 4;
            #pragma unroll
            for (int j = 0; j < 4; ++j)
                out[(size_t)(rbase + j) * OUT_DIM + col] = acc[m2][nn][j] + om;
        }
    }
}

// ---------------- fallback v1 (reg-staged from fp32 x, needs thT+WT) ---------
#define BM 128
#define BN 128
#define BK 64
__global__ __launch_bounds__(512) void k_main1(const float* __restrict__ x,
                                               const ushort* __restrict__ WT,
                                               const float* __restrict__ thT,
                                               const float* __restrict__ mu,
                                               const float* __restrict__ out_mu,
                                               float* __restrict__ out) {
    int bid  = blockIdx.x;
    int xcd  = bid & 7;
    int slot = bid >> 3;
    int n    = xcd * 4 + (slot >> 3);
    int mt   = slot & 7;
    int r0   = mt * BM;
    int cbase = n * Q_DIM;

    __shared__ ushort sA[BM * BK];
    __shared__ ushort sB[BN * BK];

    int tid  = threadIdx.x;
    int lane = tid & 63;
    int wave = tid >> 6;
    int wr   = wave >> 2;
    int wc   = wave & 3;

    f32x4 acc[4][2];
    #pragma unroll
    for (int m2 = 0; m2 < 4; ++m2)
        #pragma unroll
        for (int nn = 0; nn < 2; ++nn)
            acc[m2][nn] = (f32x4){0.f, 0.f, 0.f, 0.f};

    const int a_kq  = (tid & 15) * 4;
    const int a_rb  = tid >> 4;
    const int b_ko  = (tid & 7) * 8;
    const int b_cb  = tid >> 3;
    const int lrow  = lane & 15;
    const int lgrp  = lane >> 4;

    for (int kt = 0; kt < I_DIM / BK; ++kt) {
        int k0 = kt * BK;
        float4 thv = *(const float4*)(thT + (size_t)n * I_DIM + k0 + a_kq);
        float4 muv = *(const float4*)(mu + k0 + a_kq);
        #pragma unroll
        for (int p = 0; p < 4; ++p) {
            int row = a_rb + p * 32;
            float4 xv = *(const float4*)(x + (size_t)(r0 + row) * I_DIM + k0 + a_kq);
            float v0 = xv.x - muv.x, v1 = xv.y - muv.y, v2 = xv.z - muv.z, v3 = xv.w - muv.w;
            v0 = (fabsf(v0) >= thv.x) ? v0 : 0.f;
            v1 = (fabsf(v1) >= thv.y) ? v1 : 0.f;
            v2 = (fabsf(v2) >= thv.z) ? v2 : 0.f;
            v3 = (fabsf(v3) >= thv.w) ? v3 : 0.f;
            uint2 pk;
            pk.x = (uint32_t)f2bf(v0) | ((uint32_t)f2bf(v1) << 16);
            pk.y = (uint32_t)f2bf(v2) | ((uint32_t)f2bf(v3) << 16);
            int kbyte = (a_kq * 2) ^ ((row & 7) << 4);
            *(uint2*)((char*)sA + row * (BK * 2) + kbyte) = pk;
        }
        #pragma unroll
        for (int p = 0; p < 2; ++p) {
            int col = b_cb + p * 64;
            uint4 wv = *(const uint4*)(WT + (size_t)(cbase + col) * I_DIM + k0 + b_ko);
            int kbyte = (b_ko * 2) ^ ((col & 7) << 4);
            *(uint4*)((char*)sB + col * (BK * 2) + kbyte) = wv;
        }
        __syncthreads();
        #pragma unroll
        for (int ks = 0; ks < 2; ++ks) {
            int kb = ks * 64 + (lgrp << 4);
            bf16x8 af[4], bfr[2];
            #pragma unroll
            for (int m2 = 0; m2 < 4; ++m2) {
                int row = wr * 64 + m2 * 16 + lrow;
                af[m2] = *(const bf16x8*)((const char*)sA + row * (BK * 2) + (kb ^ ((row & 7) << 4)));
            }
            #pragma unroll
            for (int nn = 0; nn < 2; ++nn) {
                int col = wc * 32 + nn * 16 + lrow;
                bfr[nn] = *(const bf16x8*)((const char*)sB + col * (BK * 2) + (kb ^ ((col & 7) << 4)));
            }
            #pragma unroll
            for (int m2 = 0; m2 < 4; ++m2)
                #pragma unroll
                for (int nn = 0; nn < 2; ++nn)
                    acc[m2][nn] = __builtin_amdgcn_mfma_f32_16x16x32_bf16(af[m2], bfr[nn], acc[m2][nn], 0, 0, 0);
        }
        __syncthreads();
    }

    #pragma unroll
    for (int nn = 0; nn < 2; ++nn) {
        int col = cbase + wc * 32 + nn * 16 + lrow;
        float om = out_mu[col];
        #pragma unroll
        for (int m2 = 0; m2 < 4; ++m2) {
            int rbase = r0 + wr * 64 + m2 * 16 + lgrp * 4;
            #pragma unroll
            for (int j = 0; j < 4; ++j)
                out[(size_t)(rbase + j) * OUT_DIM + col] = acc[m2][nn][j] + om;
        }
    }
}

// ---------------- fallback: naive fp32 ---------------------------------------
__global__ __launch_bounds__(256) void k_naive(const float* __restrict__ x,
                                               const float* __restrict__ W,
                                               const float* __restrict__ th,
                                               const float* __restrict__ mu,
                                               const float* __restrict__ out_mu,
                                               float* __restrict__ out) {
    int idx = blockIdx.x * 256 + threadIdx.x;
    int r = idx >> 12;
    int c = idx & 4095;
    int n = c >> 7;
    float s = 0.f;
    for (int i = 0; i < I_DIM; ++i) {
        float xo = x[(size_t)r * I_DIM + i] - mu[i];
        if (fabsf(xo) >= th[i * N_STR + n])
            s += xo * W[(size_t)i * OUT_DIM + c];
    }
    out[idx] = s + out_mu[c];
}

extern "C" void kernel_launch(void* const* d_in, const int* in_sizes, int n_in,
                              void* d_out, int out_size, void* d_ws, size_t ws_size,
                              hipStream_t stream) {
    const float* x      = (const float*)d_in[0];
    const float* W      = (const float*)d_in[1];
    const float* th     = (const float*)d_in[2];
    const float* mu     = (const float*)d_in[3];
    const float* out_mu = (const float*)d_in[4];
    float* out = (float*)d_out;

    const size_t thT_b = (size_t)N_STR * I_DIM * sizeof(float);      // 512 KiB
    const size_t wT_b  = (size_t)OUT_DIM * I_DIM * sizeof(ushort);   // 32 MiB
    const size_t xb_b  = (size_t)R_TOTAL * I_DIM * sizeof(ushort);   // 8 MiB
    const size_t mb_b  = (size_t)N_STR * R_TOTAL * 512;              // 16 MiB

    if (ws_size >= thT_b + wT_b + xb_b + mb_b) {
        ushort* WT  = (ushort*)((char*)d_ws + thT_b);
        ushort* XBp = (ushort*)((char*)d_ws + thT_b + wT_b);
        uint8_t* MBp = (uint8_t*)((char*)d_ws + thT_b + wT_b + xb_b);

        k_prep2<<<2048, 256, 0, stream>>>(x, mu, th, XBp,
                                          (unsigned long long*)MBp);
        k_transpose_w<<<dim3(OUT_DIM / 64, I_DIM / 64), 256, 0, stream>>>(W, WT);
        k_main3<<<512, 512, 0, stream>>>(XBp, WT, MBp, out_mu, out);
    } else if (ws_size >= thT_b + wT_b) {
        float*  thT = (float*)d_ws;
        ushort* WT  = (ushort*)((char*)d_ws + thT_b);
        k_transpose_th<<<(N_STR * I_DIM) / 256, 256, 0, stream>>>(th, thT);
        k_transpose_w<<<dim3(OUT_DIM / 64, I_DIM / 64), 256, 0, stream>>>(W, WT);
        k_main1<<<256, 512, 0, stream>>>(x, WT, thT, mu, out_mu, out);
    } else {
        k_naive<<<(R_TOTAL * OUT_DIM) / 256, 256, 0, stream>>>(x, W, th, mu, out_mu, out);
    }
}